// Round 3
// baseline (36001.422 us; speedup 1.0000x reference)
//
#include <hip/hip_runtime.h>
#include <hip/hip_cooperative_groups.h>
#include <math.h>

namespace cg = cooperative_groups;

constexpr int kB = 64, kS = 24, kT = 96, kE = 256, kH = 512, kA = 512;
constexpr int NWG = 256, NTH = 512;  // 4 groups x 64 WGs, 1 WG/CU
constexpr int GB = 16;  // batches per group (subgroup A: 0-7, B: 8-15)
constexpr int HC = 8;   // h-cols per WG
constexpr int GC = 32;  // gate cols per WG
constexpr int HP = 516; // padded LDS row stride

// ws layout (floats). pub replaces the old h_buf (same 65536-float footprint).
constexpr int OFF_PUB = 0;                         // [2 par][4 gb][64 m][128]
constexpr int OFF_SH  = OFF_PUB + 2 * kB * kH;
constexpr int OFF_HS  = OFF_SH + 2 * kB * kH;
constexpr int OFF_Z   = OFF_HS + kB * kT * kH;
constexpr int OFF_CTX = OFF_Z + kB * kT;
constexpr int OFF_SHS = OFF_CTX + kB * kH;
constexpr int OFF_Z2  = OFF_SHS + kB * kS * kH;
constexpr int OFF_FLG = (OFF_Z2 + kB * kS + 31) & ~31;  // [4 gb][64 m] * 32 uints (128B apart)

__device__ __forceinline__ float sigmoidf(float x) { return 1.0f / (1.0f + expf(-x)); }
__device__ __forceinline__ float dot4(float4 a, float4 b) {
  return a.x * b.x + a.y * b.y + a.z * b.z + a.w * b.w;
}
__device__ __forceinline__ float2 aload2(const float* p) {
  unsigned long long u = __hip_atomic_load((const unsigned long long*)p,
                                           __ATOMIC_RELAXED, __HIP_MEMORY_SCOPE_AGENT);
  union { unsigned long long u; float2 f; } cv; cv.u = u;
  return cv.f;
}
__device__ __forceinline__ float aload1(const float* p) {
  return __hip_atomic_load(p, __ATOMIC_RELAXED, __HIP_MEMORY_SCOPE_AGENT);
}
__device__ __forceinline__ void astore(float* p, float v) {
  __hip_atomic_store(p, v, __ATOMIC_RELAXED, __HIP_MEMORY_SCOPE_AGENT);
}
__device__ __forceinline__ unsigned aloadu(const unsigned* p) {
  return __hip_atomic_load(p, __ATOMIC_RELAXED, __HIP_MEMORY_SCOPE_AGENT);
}
__device__ __forceinline__ void astoreu(unsigned* p, unsigned v) {
  __hip_atomic_store(p, v, __ATOMIC_RELAXED, __HIP_MEMORY_SCOPE_AGENT);
}

__global__ __launch_bounds__(NTH) void ha_kernel(
    const int* __restrict__ captions, const int* __restrict__ masks,
    const float* __restrict__ embed_W,
    const float* __restrict__ w_Wih, const float* __restrict__ w_Whh,
    const float* __restrict__ w_bih, const float* __restrict__ w_bhh,
    const float* __restrict__ s_Wih, const float* __restrict__ s_Whh,
    const float* __restrict__ s_bih, const float* __restrict__ s_bhh,
    const float* __restrict__ wa_Wk, const float* __restrict__ wa_Wv,
    const float* __restrict__ sa_Wk, const float* __restrict__ sa_Wv,
    float* __restrict__ out, float* __restrict__ ws) {
  cg::grid_group grid = cg::this_grid();
  const int g = blockIdx.x, tid = threadIdx.x;
  const int gb = g & 3, gm = g >> 2;   // group (4), member (64)
  const int B0 = GB * gb;
  const int hc0 = HC * gm;
  const int jj = tid >> 6;
  const int lane = tid & 63, cc = lane >> 3, bp = lane & 7;

  float* pub = ws + OFF_PUB;
  float* sh_buf = ws + OFF_SH;
  float* hs_buf = ws + OFF_HS;
  float* z_buf = ws + OFF_Z;
  float* ctx_ws = ws + OFF_CTX;
  float* sent_hs = ws + OFF_SHS;
  float* z2_buf = ws + OFF_Z2;
  unsigned* flags = (unsigned*)(ws + OFF_FLG);
  unsigned* myflag = &flags[(gb * 64 + gm) * 32];

  // LDS ~125 KB (1 WG/CU)
  __shared__ __align__(16) float whh_s[GC][HP];          // 66 KB, LDS-resident Whh slice
  __shared__ float bias_s[GC];
  __shared__ __align__(16) float hstage[GB][HP];         // rows 0-7: h_A, 8-15: h_B; aliased by attn/sent staging
  __shared__ __align__(16) float partsU[4608];           // A: [0,2112), B: [2112,4224); sent: 8*576
  __shared__ float gates_s[GC][GB];
  __shared__ int masks_s[GB * kT];
  __shared__ float c_s[HC][GB], hown_s[HC][GB], sc_s[HC][GB];
  __shared__ float soft_s[kT], red_s[96];

  float* attn_f = &hstage[0][0];
  float* part16 = &partsU[0];

  auto grow = [&](int c) { return (c >> 3) * kH + hc0 + (c & 7); };

  // ---- init ----
  for (int idx = tid; idx < GC * kH; idx += NTH) {
    int r = idx >> 9, k = idx & (kH - 1);
    int c_log = 4 * (r & 7) + (r >> 3);
    whh_s[r][k] = w_Whh[(size_t)grow(c_log) * kH + k];
  }
  if (tid < GC) bias_s[tid] = w_bih[grow(tid)] + w_bhh[grow(tid)];
  if (tid < HC * GB) {
    c_s[tid >> 4][tid & 15] = 0.f;
    hown_s[tid >> 4][tid & 15] = 0.f;
    sc_s[tid >> 4][tid & 15] = 0.f;
  }
  for (int idx = tid; idx < GB * HP; idx += NTH) hstage[idx / HP][idx % HP] = 0.f;
  {
    int idx = g * NTH + tid;   // 131072 total = pub(65536) + sh(65536)
    if (idx < 2 * kB * kH) pub[idx] = 0.f;
    else sh_buf[idx - 2 * kB * kH] = 0.f;
  }
  if (g == 0)
    for (int idx = tid; idx < 4 * 64 * 32; idx += NTH) flags[idx] = 0u;
  grid.sync();

  // Direct all-poll barrier (no leader hop). Monotone shared sequence n;
  // A-half, B-half and phase arrivals all bump the same per-WG flag.
  auto wait_flags = [&](unsigned nn) {
    if (tid < 64) {
      while (aloadu(&flags[(gb * 64 + tid) * 32]) < nn) __builtin_amdgcn_s_sleep(2);
    }
    __syncthreads();
  };

  // Wih GEMV register partials for both subgroups (batch bp / 8+bp)
  float xpA[4], xpB[4];
  auto prefetch = [&](int s2, int t2) {
    const int capA = captions[((B0 + bp) * kS + s2) * kT + t2];
    const int capB = captions[((B0 + 8 + bp) * kS + s2) * kT + t2];
    const float4* __restrict__ xA = (const float4*)(embed_W + (size_t)capA * kE);
    const float4* __restrict__ xB = (const float4*)(embed_W + (size_t)capB * kE);
#pragma unroll
    for (int d = 0; d < 4; ++d) { xpA[d] = 0.f; xpB[d] = 0.f; }
#pragma unroll 2
    for (int u = 0; u < 8; ++u) {
      const int ec = 8 * jj + u;
      const float4 xvA = xA[ec], xvB = xB[ec];
#pragma unroll
      for (int d = 0; d < 4; ++d) {
        const float4 w = *(const float4*)&w_Wih[(size_t)grow(4 * cc + d) * kE + 4 * ec];
        xpA[d] += dot4(w, xvA);
        xpB[d] += dot4(w, xvB);
      }
    }
  };

  // word GEMV for one subgroup: parts[jj][lane] = xp + Whh·h
  auto word_gemv = [&](int rowbase, float* parts, const float* xp) {
    float a0 = xp[0], a1 = xp[1], a2 = xp[2], a3 = xp[3];
    const float* hrow = &hstage[rowbase + bp][64 * jj];
    const float* w0 = &whh_s[0 * 8 + cc][64 * jj];
    const float* w1 = &whh_s[1 * 8 + cc][64 * jj];
    const float* w2 = &whh_s[2 * 8 + cc][64 * jj];
    const float* w3 = &whh_s[3 * 8 + cc][64 * jj];
#pragma unroll 4
    for (int u = 0; u < 16; ++u) {
      const float4 hv = *(const float4*)&hrow[4 * u];
      a0 += dot4(*(const float4*)&w0[4 * u], hv);
      a1 += dot4(*(const float4*)&w1[4 * u], hv);
      a2 += dot4(*(const float4*)&w2[4 * u], hv);
      a3 += dot4(*(const float4*)&w3[4 * u], hv);
    }
    *(float4*)&parts[jj * 264 + lane * 4] = make_float4(a0, a1, a2, a3);
  };

  // word cell for tid<64: reduce parts, LSTM cell, publish hn (coalesced 256B).
  // Returns the (lazy) hs value.
  auto word_cell = [&](int sub, const float* parts, float* pubw, int t) -> float {
    const int bl = tid >> 3, hcl = tid & 7, bg = sub * 8 + bl;
    float gg4[4];
#pragma unroll
    for (int g2 = 0; g2 < 4; ++g2) {
      const int c = g2 * 8 + hcl, cc2 = c >> 2, d = c & 3;
      float ssum = bias_s[c];
#pragma unroll
      for (int j = 0; j < 8; ++j) ssum += parts[j * 264 + (cc2 * 8 + bl) * 4 + d];
      gg4[g2] = ssum;
    }
    const float cold = c_s[hcl][bg];
    const float c2 = sigmoidf(gg4[1]) * cold + sigmoidf(gg4[0]) * tanhf(gg4[2]);
    const float h2 = sigmoidf(gg4[3]) * tanhf(c2);
    const int m = masks_s[bg * kT + t];
    const float cn = m ? c2 : cold;
    const float hn = m ? h2 : hown_s[hcl][bg];
    c_s[hcl][bg] = cn;
    hown_s[hcl][bg] = hn;
    astore(&pubw[gm * 128 + sub * 64 + tid], hn);   // full-line coalesced publish
    return m ? h2 : 0.f;
  };

  prefetch(0, 0);
  unsigned n = 0;
  int gstep = 0;
  for (int s = 0; s < kS; ++s) {
    // per-sentence: preload masks; restage h from pub (phases clobbered hstage)
    for (int idx = tid; idx < GB * kT; idx += NTH)
      masks_s[idx] = masks[((B0 + idx / kT) * kS + s) * kT + (idx % kT)];
    if (s > 0) {
      const float* pubr = pub + ((size_t)(gstep & 1) * 4 + gb) * 8192;
#pragma unroll
      for (int it = 0; it < 8; ++it) {
        const int idx = it * 1024 + tid * 2;     // 0..8191
        const int m2 = idx >> 7, rem = idx & 127;
        float2 v = aload2(&pubr[m2 * 128 + rem]);
        *(float2*)&hstage[rem >> 3][m2 * 8 + (rem & 7)] = v;
      }
    }
    __syncthreads();

    // ================= word LSTM: 96 steps, A/B pipelined =================
    for (int t = 0; t < kT; ++t, ++gstep) {
      float* pubw = pub + ((size_t)((gstep + 1) & 1) * 4 + gb) * 8192;

      // ---- A half ----
      word_gemv(0, &partsU[0], xpA);
      __syncthreads();
      float hsvA = 0.f;
      if (tid < 64) hsvA = word_cell(0, &partsU[0], pubw, t);
      __syncthreads();  // drains A publish
      ++n;
      if (tid == 0) astoreu(myflag, n);          // arrive A
      if (tid < 64)
        astore(&hs_buf[((size_t)(B0 + (tid >> 3)) * kT + t) * kH + hc0 + (tid & 7)], hsvA);

      // ---- B half ----
      word_gemv(8, &partsU[2112], xpB);
      __syncthreads();
      float hsvB = 0.f;
      if (tid < 64) hsvB = word_cell(1, &partsU[2112], pubw, t);
      __syncthreads();  // drains B publish
      ++n;
      if (tid == 0) astoreu(myflag, n);          // arrive B
      if (tid < 64)
        astore(&hs_buf[((size_t)(B0 + 8 + (tid >> 3)) * kT + t) * kH + hc0 + (tid & 7)], hsvB);

      if (t < kT - 1) prefetch(s, t + 1);        // overlaps propagation

      // wait + stage A (arriveA was ~1.5µs ago)
      wait_flags(n - 1);
#pragma unroll
      for (int it = 0; it < 4; ++it) {
        const int aidx = it * 1024 + tid * 2;    // 0..4095
        const int m2 = aidx >> 6, rem = aidx & 63;
        float2 v = aload2(&pubw[m2 * 128 + rem]);
        *(float2*)&hstage[rem >> 3][m2 * 8 + (rem & 7)] = v;
      }
      // wait + stage B
      wait_flags(n);
#pragma unroll
      for (int it = 0; it < 4; ++it) {
        const int aidx = it * 1024 + tid * 2;
        const int m2 = aidx >> 6, rem = aidx & 63;
        float2 v = aload2(&pubw[m2 * 128 + 64 + rem]);
        *(float2*)&hstage[8 + (rem >> 3)][m2 * 8 + (rem & 7)] = v;
      }
      __syncthreads();  // staging visible for next step
    }

    // phase barrier: drains lazy hs_buf stores before attention reads them
    ++n;
    __syncthreads();
    if (tid == 0) astoreu(myflag, n);
    wait_flags(n);

    // ================= word attention: z[b,t] (group-local) =================
    {
      const int ab = gm >> 2, at0 = (gm & 3) * 24;
      const int bg = B0 + ab;
      for (int half = 0; half < 2; ++half) {
        const int tb = at0 + half * 12;
        for (int idx = tid; idx < 12 * 256; idx += NTH) {
          int pp = idx >> 8, hh2 = (idx & 255) * 2;
          float2 v = aload2(&hs_buf[((size_t)bg * kT + tb + pp) * kH + hh2]);
          *(float2*)&attn_f[pp * HP + hh2] = v;
        }
        __syncthreads();
        const int aa = tid;
        float dacc[12];
#pragma unroll
        for (int p = 0; p < 12; ++p) dacc[p] = 0.f;
        const float4* __restrict__ wk = (const float4*)(wa_Wk + (size_t)aa * kH);
        for (int k = 0; k < kH / 4; ++k) {
          float4 w = wk[k];
#pragma unroll
          for (int p = 0; p < 12; ++p)
            dacc[p] += dot4(w, *(const float4*)&attn_f[p * HP + k * 4]);
        }
        const float wv = wa_Wv[aa];
        const int ln = tid & 63, wid = tid >> 6;
#pragma unroll
        for (int p = 0; p < 12; ++p) {
          float v = wv * tanhf(dacc[p]);
          v += __shfl_down(v, 32); v += __shfl_down(v, 16); v += __shfl_down(v, 8);
          v += __shfl_down(v, 4);  v += __shfl_down(v, 2);  v += __shfl_down(v, 1);
          if (ln == 0) red_s[wid * 12 + p] = v;
        }
        __syncthreads();
        if (tid < 12) {
          float sum = 0.f;
#pragma unroll
          for (int w = 0; w < 8; ++w) sum += red_s[w * 12 + tid];
          astore(&z_buf[bg * kT + tb + tid], sum);
        }
        __syncthreads();
      }
    }
    ++n;
    __syncthreads();
    if (tid == 0) astoreu(myflag, n);
    wait_flags(n);

    // ================= softmax over T + ctx =================
    if (gm < GB) {
      const int b = B0 + gm;
      if (tid < kT) soft_s[tid] = aload1(&z_buf[b * kT + tid]);
      __syncthreads();
      float mx = -1e30f;
      for (int i = 0; i < kT; ++i) mx = fmaxf(mx, soft_s[i]);
      float den = 0.f;
      for (int i = 0; i < kT; ++i) den += expf(soft_s[i] - mx);
      __syncthreads();
      if (tid < kT) soft_s[tid] = expf(soft_s[tid] - mx) / den;
      __syncthreads();
      {
        const int h0 = tid;
        float a0 = 0.f, a1 = 0.f, a2 = 0.f, a3 = 0.f;
        for (int tt = 0; tt < kT; tt += 4) {
          a0 += soft_s[tt + 0] * aload1(&hs_buf[((size_t)b * kT + tt + 0) * kH + h0]);
          a1 += soft_s[tt + 1] * aload1(&hs_buf[((size_t)b * kT + tt + 1) * kH + h0]);
          a2 += soft_s[tt + 2] * aload1(&hs_buf[((size_t)b * kT + tt + 2) * kH + h0]);
          a3 += soft_s[tt + 3] * aload1(&hs_buf[((size_t)b * kT + tt + 3) * kH + h0]);
        }
        astore(&ctx_ws[b * kH + h0], (a0 + a1) + (a2 + a3));
      }
    }
    ++n;
    __syncthreads();
    if (tid == 0) astoreu(myflag, n);
    wait_flags(n);

    // ================= sentence LSTM (two-pass GEMV, K1 layout) =================
    {
      const int b0s = 2 * bp, b1s = b0s + 1;
      float (*h_s)[HP] = reinterpret_cast<float (*)[HP]>(&hstage[0][0]);
      auto stage16 = [&](const float* src) {
#pragma unroll
        for (int r = 0; r < 8; ++r) {
          const int f = (r * 512 + tid) * 2;
          const int b = f >> 9, k = f & (kH - 1);
          float2 v = aload2(src + b * kH + k);
          const int ch = (((k >> 2) + (b >> 1)) & 127) * 4 + (k & 3);
          *(float2*)&h_s[b][ch] = v;
        }
      };
      float acc[4][2];
#pragma unroll
      for (int d = 0; d < 4; ++d) { acc[d][0] = 0.f; acc[d][1] = 0.f; }
      stage16(ctx_ws + B0 * kH);  // pass A: x = ctx
      __syncthreads();
#pragma unroll 2
      for (int u = 0; u < 16; ++u) {
        const int chunk = 16 * jj + u;
        const int offH = ((chunk + bp) & 127) * 4;
        const float4 x0v = *(const float4*)&h_s[b0s][offH];
        const float4 x1v = *(const float4*)&h_s[b1s][offH];
#pragma unroll
        for (int d = 0; d < 4; ++d) {
          const float4 w = *(const float4*)&s_Wih[(size_t)grow(4 * cc + d) * kH + chunk * 4];
          acc[d][0] += dot4(w, x0v);
          acc[d][1] += dot4(w, x1v);
        }
      }
      __syncthreads();
      stage16(sh_buf + (s & 1) * kB * kH + B0 * kH);  // pass B: h = sh
      __syncthreads();
#pragma unroll 2
      for (int u = 0; u < 16; ++u) {
        const int chunk = 16 * jj + u;
        const int offH = ((chunk + bp) & 127) * 4;
        const float4 h0v = *(const float4*)&h_s[b0s][offH];
        const float4 h1v = *(const float4*)&h_s[b1s][offH];
#pragma unroll
        for (int d = 0; d < 4; ++d) {
          const float4 w = *(const float4*)&s_Whh[(size_t)grow(4 * cc + d) * kH + chunk * 4];
          acc[d][0] += dot4(w, h0v);
          acc[d][1] += dot4(w, h1v);
        }
      }
#pragma unroll
      for (int d = 0; d < 4; ++d) {
        part16[jj * 576 + lane * 9 + d * 2 + 0] = acc[d][0];
        part16[jj * 576 + lane * 9 + d * 2 + 1] = acc[d][1];
      }
      __syncthreads();
      {
        const int c = tid >> 4, b = tid & 15;
        const int lp = (c >> 2) * 8 + (b >> 1), sl = (c & 3) * 2 + (b & 1);
        const int row = grow(c);
        float sum = s_bih[row] + s_bhh[row];
#pragma unroll
        for (int j = 0; j < 8; ++j) sum += part16[j * 576 + lp * 9 + sl];
        gates_s[c][b] = sum;
      }
      __syncthreads();
      if (tid < HC * GB) {
        const int hcl = tid >> 4, b = tid & 15;
        const float gi = gates_s[hcl][b], gf = gates_s[8 + hcl][b];
        const float gg = gates_s[16 + hcl][b], go = gates_s[24 + hcl][b];
        const float c2 = sigmoidf(gf) * sc_s[hcl][b] + sigmoidf(gi) * tanhf(gg);
        const float h2 = sigmoidf(go) * tanhf(c2);
        sc_s[hcl][b] = c2;
        const int col = hc0 + hcl;
        astore(&sh_buf[((s + 1) & 1) * kB * kH + (B0 + b) * kH + col], h2);
        astore(&sent_hs[((size_t)(B0 + b) * kS + s) * kH + col], h2);
      }
    }
    ++n;
    __syncthreads();
    if (tid == 0) astoreu(myflag, n);
    if (s < kS - 1) prefetch(s + 1, 0);
    wait_flags(n);
  }

  // ================= final attention over S (group-local) =================
  {
    const int pair0 = gm * 6;
    for (int idx = tid; idx < 6 * 256; idx += NTH) {
      int pp = idx >> 8, hh2 = (idx & 255) * 2;
      const int pr = pair0 + pp;
      float2 v = aload2(&sent_hs[((size_t)(B0 + pr / kS) * kS + pr % kS) * kH + hh2]);
      *(float2*)&attn_f[pp * HP + hh2] = v;
    }
    __syncthreads();
    const int aa = tid;
    float dacc[6];
#pragma unroll
    for (int p = 0; p < 6; ++p) dacc[p] = 0.f;
    const float4* __restrict__ wk = (const float4*)(sa_Wk + (size_t)aa * kH);
    for (int k = 0; k < kH / 4; ++k) {
      float4 w = wk[k];
#pragma unroll
      for (int p = 0; p < 6; ++p)
        dacc[p] += dot4(w, *(const float4*)&attn_f[p * HP + k * 4]);
    }
    const float wv = sa_Wv[aa];
    const int ln = tid & 63, wid = tid >> 6;
#pragma unroll
    for (int p = 0; p < 6; ++p) {
      float v = wv * tanhf(dacc[p]);
      v += __shfl_down(v, 32); v += __shfl_down(v, 16); v += __shfl_down(v, 8);
      v += __shfl_down(v, 4);  v += __shfl_down(v, 2);  v += __shfl_down(v, 1);
      if (ln == 0) red_s[wid * 6 + p] = v;
    }
    __syncthreads();
    if (tid < 6) {
      float sum = 0.f;
#pragma unroll
      for (int w = 0; w < 8; ++w) sum += red_s[w * 6 + tid];
      astore(&z2_buf[B0 * kS + pair0 + tid], sum);
    }
  }
  ++n;
  __syncthreads();
  if (tid == 0) astoreu(myflag, n);
  wait_flags(n);

  // ================= final softmax + outputs =================
  if (gm < GB) {
    const int b = B0 + gm;
    if (tid < kS) soft_s[tid] = aload1(&z2_buf[b * kS + tid]);
    __syncthreads();
    float mx = -1e30f;
    for (int i = 0; i < kS; ++i) mx = fmaxf(mx, soft_s[i]);
    float den = 0.f;
    for (int i = 0; i < kS; ++i) den += expf(soft_s[i] - mx);
    __syncthreads();
    if (tid < kS) {
      float al = expf(soft_s[tid] - mx) / den;
      soft_s[tid] = al;
      out[kB * kH + b * kS + tid] = al;  // alpha
    }
    __syncthreads();
    {
      const int h0 = tid;
      float acc = 0.f;
      for (int s2 = 0; s2 < kS; ++s2)
        acc += soft_s[s2] * aload1(&sent_hs[((size_t)b * kS + s2) * kH + h0]);
      out[b * kH + h0] = acc;  // context
    }
  }
}

extern "C" void kernel_launch(void* const* d_in, const int* in_sizes, int n_in,
                              void* d_out, int out_size, void* d_ws, size_t ws_size,
                              hipStream_t stream) {
  (void)in_sizes; (void)n_in; (void)out_size; (void)ws_size;
  const int* captions = (const int*)d_in[0];
  const int* masks = (const int*)d_in[1];
  const float* embed_W = (const float*)d_in[2];
  const float* w_Wih = (const float*)d_in[3];
  const float* w_Whh = (const float*)d_in[4];
  const float* w_bih = (const float*)d_in[5];
  const float* w_bhh = (const float*)d_in[6];
  const float* s_Wih = (const float*)d_in[7];
  const float* s_Whh = (const float*)d_in[8];
  const float* s_bih = (const float*)d_in[9];
  const float* s_bhh = (const float*)d_in[10];
  const float* wa_Wk = (const float*)d_in[11];
  const float* wa_Wv = (const float*)d_in[12];
  const float* sa_Wk = (const float*)d_in[13];
  const float* sa_Wv = (const float*)d_in[14];
  float* out = (float*)d_out;
  float* ws = (float*)d_ws;

  void* args[] = {&captions, &masks, &embed_W, &w_Wih, &w_Whh, &w_bih, &w_bhh,
                  &s_Wih, &s_Whh, &s_bih, &s_bhh, &wa_Wk, &wa_Wv, &sa_Wk, &sa_Wv,
                  &out, &ws};
  hipLaunchCooperativeKernel((void*)ha_kernel, dim3(NWG), dim3(NTH), args, 0, stream);
}

// Round 4
// 32060.120 us; speedup vs baseline: 1.1229x; 1.1229x over previous
//
#include <hip/hip_runtime.h>
#include <hip/hip_cooperative_groups.h>
#include <math.h>

namespace cg = cooperative_groups;

constexpr int kB = 64, kS = 24, kT = 96, kE = 256, kH = 512, kA = 512;
constexpr int NWG = 256, NTH = 512;  // 4 groups x 64 WGs, 1 WG/CU
constexpr int GB = 16;  // batches per group
constexpr int HC = 8;   // h-cols per WG
constexpr int GC = 32;  // gate cols per WG
constexpr int HP = 516; // padded LDS row stride

// ws layout (floats). pub: [2 parity][4 gb][64 m][128] = h published per WG,
// linear in (m, b, hcl): pub[m*128 + b*8 + hcl] = h[b][8m+hcl].
constexpr int OFF_PUB = 0;
constexpr int OFF_SH  = OFF_PUB + 2 * kB * kH;
constexpr int OFF_HS  = OFF_SH + 2 * kB * kH;
constexpr int OFF_Z   = OFF_HS + kB * kT * kH;
constexpr int OFF_CTX = OFF_Z + kB * kT;
constexpr int OFF_SHS = OFF_CTX + kB * kH;
constexpr int OFF_Z2  = OFF_SHS + kB * kS * kH;
constexpr int OFF_FLG = (OFF_Z2 + kB * kS + 31) & ~31;  // [4 gb][64 m] * 32 uints

__device__ __forceinline__ float sigmoidf(float x) { return 1.0f / (1.0f + expf(-x)); }
__device__ __forceinline__ float dot4(float4 a, float4 b) {
  return a.x * b.x + a.y * b.y + a.z * b.z + a.w * b.w;
}
__device__ __forceinline__ float2 aload2(const float* p) {
  unsigned long long u = __hip_atomic_load((const unsigned long long*)p,
                                           __ATOMIC_RELAXED, __HIP_MEMORY_SCOPE_AGENT);
  union { unsigned long long u; float2 f; } cv; cv.u = u;
  return cv.f;
}
__device__ __forceinline__ float aload1(const float* p) {
  return __hip_atomic_load(p, __ATOMIC_RELAXED, __HIP_MEMORY_SCOPE_AGENT);
}
__device__ __forceinline__ void astore(float* p, float v) {
  __hip_atomic_store(p, v, __ATOMIC_RELAXED, __HIP_MEMORY_SCOPE_AGENT);
}
__device__ __forceinline__ unsigned aloadu(const unsigned* p) {
  return __hip_atomic_load(p, __ATOMIC_RELAXED, __HIP_MEMORY_SCOPE_AGENT);
}
__device__ __forceinline__ void astoreu(unsigned* p, unsigned v) {
  __hip_atomic_store(p, v, __ATOMIC_RELAXED, __HIP_MEMORY_SCOPE_AGENT);
}

__global__ __launch_bounds__(NTH) void ha_kernel(
    const int* __restrict__ captions, const int* __restrict__ masks,
    const float* __restrict__ embed_W,
    const float* __restrict__ w_Wih, const float* __restrict__ w_Whh,
    const float* __restrict__ w_bih, const float* __restrict__ w_bhh,
    const float* __restrict__ s_Wih, const float* __restrict__ s_Whh,
    const float* __restrict__ s_bih, const float* __restrict__ s_bhh,
    const float* __restrict__ wa_Wk, const float* __restrict__ wa_Wv,
    const float* __restrict__ sa_Wk, const float* __restrict__ sa_Wv,
    float* __restrict__ out, float* __restrict__ ws) {
  cg::grid_group grid = cg::this_grid();
  const int g = blockIdx.x, tid = threadIdx.x;
  const int gb = g & 3, gm = g >> 2;   // group (4), member (64)
  const int B0 = GB * gb;
  const int hc0 = HC * gm;
  const int jj = tid >> 6;
  const int lane = tid & 63, cc = lane >> 3, bp = lane & 7;
  const int b0 = 2 * bp, b1 = b0 + 1;

  float* pub = ws + OFF_PUB;
  float* sh_buf = ws + OFF_SH;
  float* hs_buf = ws + OFF_HS;
  float* z_buf = ws + OFF_Z;
  float* ctx_ws = ws + OFF_CTX;
  float* sent_hs = ws + OFF_SHS;
  float* z2_buf = ws + OFF_Z2;
  unsigned* flags = (unsigned*)(ws + OFF_FLG);
  unsigned* myflag = &flags[(gb * 64 + gm) * 32];

  // LDS ~128 KB, 1 WG/CU
  __shared__ __align__(16) float whh_s[GC][HP];   // LDS-resident Whh slice (66 KB)
  __shared__ float bias_s[GC];
  __shared__ __align__(16) float hstage[GB][HP];  // h tile; aliased by attn/sent staging
  __shared__ __align__(16) float part_f[8 * 576];
  __shared__ float gates_s[GC][GB];
  __shared__ int masks_s[GB * kT];
  __shared__ float c_s[HC][GB], hown_s[HC][GB], sc_s[HC][GB];
  __shared__ float soft_s[kT], red_s[96];

  float (*h_s)[HP] = reinterpret_cast<float (*)[HP]>(&hstage[0][0]);
  float* attn_f = &hstage[0][0];

  auto grow = [&](int c) { return (c >> 3) * kH + hc0 + (c & 7); };

  // ---- init ----
  for (int idx = tid; idx < GC * kH; idx += NTH) {
    int r = idx >> 9, k = idx & (kH - 1);
    int c_log = 4 * (r & 7) + (r >> 3);
    whh_s[r][k] = w_Whh[(size_t)grow(c_log) * kH + k];
  }
  if (tid < GC) bias_s[tid] = w_bih[grow(tid)] + w_bhh[grow(tid)];
  if (tid < HC * GB) {
    c_s[tid >> 4][tid & 15] = 0.f;
    hown_s[tid >> 4][tid & 15] = 0.f;
    sc_s[tid >> 4][tid & 15] = 0.f;
  }
  for (int idx = tid; idx < GB * HP; idx += NTH) hstage[idx / HP][idx % HP] = 0.f;
  {
    int idx = g * NTH + tid;   // pub (65536) + sh (65536)
    if (idx < 2 * kB * kH) pub[idx] = 0.f;
    else sh_buf[idx - 2 * kB * kH] = 0.f;
  }
  if (g == 0)
    for (int idx = tid; idx < 4 * 64 * 32; idx += NTH) flags[idx] = 0u;
  grid.sync();

  // Barrier: per-WG monotone flag; each WG's first 64 threads poll all 64
  // member flags directly (no leader hop).
  auto wait_flags = [&](unsigned nn) {
    if (tid < 64) {
      while (aloadu(&flags[(gb * 64 + tid) * 32]) < nn) __builtin_amdgcn_s_sleep(8);
    }
    __syncthreads();
  };

  // stage pub slab -> rotated hstage. src index == linear index (coalesced).
  // dest: h[b][k] -> h_s[b][ ((k>>2)+(b>>1) & 127)*4 + (k&3) ]
  auto stage_pub = [&](const float* slab) {
#pragma unroll
    for (int it = 0; it < 8; ++it) {
      const int lin = it * 1024 + tid * 2;
      const int k = ((lin >> 7) << 3) | (lin & 7);
      const int b = (lin >> 3) & 15;
      float2 v = aload2(&slab[lin]);
      const int ch = (((k >> 2) + (b >> 1)) & 127) * 4 + (k & 3);
      *(float2*)&h_s[b][ch] = v;
    }
  };

  // K1's linear stager (for ctx / sh in the sentence phase)
  auto stage16_lin = [&](const float* src) {
#pragma unroll
    for (int r = 0; r < 8; ++r) {
      const int f = (r * 512 + tid) * 2;
      const int b = f >> 9, k = f & (kH - 1);
      float2 v = aload2(src + b * kH + k);
      const int ch = (((k >> 2) + (b >> 1)) & 127) * 4 + (k & 3);
      *(float2*)&h_s[b][ch] = v;
    }
  };

  float xp[4][2];
  auto prefetch = [&](int s2, int t2) {
    const int cap0 = captions[((B0 + b0) * kS + s2) * kT + t2];
    const int cap1 = captions[((B0 + b1) * kS + s2) * kT + t2];
    const float4* __restrict__ x0 = (const float4*)(embed_W + (size_t)cap0 * kE);
    const float4* __restrict__ x1 = (const float4*)(embed_W + (size_t)cap1 * kE);
#pragma unroll
    for (int d = 0; d < 4; ++d) { xp[d][0] = 0.f; xp[d][1] = 0.f; }
#pragma unroll 2
    for (int u = 0; u < 8; ++u) {
      const int ec = 8 * jj + u;
      const float4 xv0 = x0[ec], xv1 = x1[ec];
#pragma unroll
      for (int d = 0; d < 4; ++d) {
        const float4 w = *(const float4*)&w_Wih[(size_t)grow(4 * cc + d) * kE + 4 * ec];
        xp[d][0] += dot4(w, xv0);
        xp[d][1] += dot4(w, xv1);
      }
    }
  };

  prefetch(0, 0);
  unsigned n = 0;
  int gstep = 0;
  for (int s = 0; s < kS; ++s) {
    // per-sentence: masks to LDS; restage h from pub (phases clobbered hstage)
    for (int idx = tid; idx < GB * kT; idx += NTH)
      masks_s[idx] = masks[((B0 + idx / kT) * kS + s) * kT + (idx % kT)];
    if (s > 0) stage_pub(pub + ((size_t)(gstep & 1) * 4 + gb) * 8192);
    __syncthreads();

    // ================= word LSTM: 96 steps, one barrier each =================
    for (int t = 0; t < kT; ++t, ++gstep) {
      float* pubw = pub + ((size_t)((gstep + 1) & 1) * 4 + gb) * 8192;

      // GEMV (K1 rotated layout, conflict-free)
      float acc[4][2];
#pragma unroll
      for (int d = 0; d < 4; ++d) { acc[d][0] = xp[d][0]; acc[d][1] = xp[d][1]; }
#pragma unroll 4
      for (int u = 0; u < 16; ++u) {
        const int chunk = 16 * jj + u;
        const int offW = chunk * 4;
        const int offH = ((chunk + bp) & 127) * 4;
        const float4 h0v = *(const float4*)&h_s[b0][offH];
        const float4 h1v = *(const float4*)&h_s[b1][offH];
#pragma unroll
        for (int d = 0; d < 4; ++d) {
          const float4 w = *(const float4*)&whh_s[d * 8 + cc][offW];
          acc[d][0] += dot4(w, h0v);
          acc[d][1] += dot4(w, h1v);
        }
      }
#pragma unroll
      for (int d = 0; d < 4; ++d) {
        part_f[jj * 576 + lane * 9 + d * 2 + 0] = acc[d][0];
        part_f[jj * 576 + lane * 9 + d * 2 + 1] = acc[d][1];
      }
      __syncthreads();
      // reduce over jj
      {
        const int c = tid >> 4, b = tid & 15;
        const int lp = (c >> 2) * 8 + (b >> 1), sl = (c & 3) * 2 + (b & 1);
        float sum = bias_s[c];
#pragma unroll
        for (int j = 0; j < 8; ++j) sum += part_f[j * 576 + lp * 9 + sl];
        gates_s[c][b] = sum;
      }
      __syncthreads();
      // cell + coalesced publish; hs value kept in register (lazy store)
      float hsv = 0.f;
      if (tid < HC * GB) {
        const int hcl = tid >> 4, b = tid & 15;
        const float gi = gates_s[hcl][b], gf = gates_s[8 + hcl][b];
        const float gg = gates_s[16 + hcl][b], go = gates_s[24 + hcl][b];
        const float cold = c_s[hcl][b];
        const float c2 = sigmoidf(gf) * cold + sigmoidf(gi) * tanhf(gg);
        const float h2 = sigmoidf(go) * tanhf(c2);
        const int m = masks_s[b * kT + t];
        const float cn = m ? c2 : cold;
        const float hn = m ? h2 : hown_s[hcl][b];
        c_s[hcl][b] = cn;
        hown_s[hcl][b] = hn;
        astore(&pubw[gm * 128 + b * 8 + hcl], hn);  // 512B/WG, 4 full lines
        hsv = m ? h2 : 0.f;
      }
      ++n;
      __syncthreads();                        // drains publish
      if (tid == 0) astoreu(myflag, n);       // arrive
      // cover work while the flag propagates:
      if (tid < HC * GB) {
        const int hcl = tid >> 4, b = tid & 15;
        astore(&hs_buf[((size_t)(B0 + b) * kT + t) * kH + hc0 + hcl], hsv);
      }
      if (t < kT - 1) prefetch(s, t + 1);
      wait_flags(n);
      stage_pub(pubw);
      __syncthreads();
    }

    // phase barrier (drains lazy hs stores before attention reads)
    ++n;
    __syncthreads();
    if (tid == 0) astoreu(myflag, n);
    wait_flags(n);

    // ================= word attention: z[b,t] (group-local) =================
    {
      const int ab = gm >> 2, at0 = (gm & 3) * 24;
      const int bg = B0 + ab;
      for (int half = 0; half < 2; ++half) {
        const int tb = at0 + half * 12;
        for (int idx = tid; idx < 12 * 256; idx += NTH) {
          int pp = idx >> 8, hh2 = (idx & 255) * 2;
          float2 v = aload2(&hs_buf[((size_t)bg * kT + tb + pp) * kH + hh2]);
          *(float2*)&attn_f[pp * HP + hh2] = v;
        }
        __syncthreads();
        const int aa = tid;
        float dacc[12];
#pragma unroll
        for (int p = 0; p < 12; ++p) dacc[p] = 0.f;
        const float4* __restrict__ wk = (const float4*)(wa_Wk + (size_t)aa * kH);
        for (int k = 0; k < kH / 4; ++k) {
          float4 w = wk[k];
#pragma unroll
          for (int p = 0; p < 12; ++p)
            dacc[p] += dot4(w, *(const float4*)&attn_f[p * HP + k * 4]);
        }
        const float wv = wa_Wv[aa];
        const int ln = tid & 63, wid = tid >> 6;
#pragma unroll
        for (int p = 0; p < 12; ++p) {
          float v = wv * tanhf(dacc[p]);
          v += __shfl_down(v, 32); v += __shfl_down(v, 16); v += __shfl_down(v, 8);
          v += __shfl_down(v, 4);  v += __shfl_down(v, 2);  v += __shfl_down(v, 1);
          if (ln == 0) red_s[wid * 12 + p] = v;
        }
        __syncthreads();
        if (tid < 12) {
          float sum = 0.f;
#pragma unroll
          for (int w = 0; w < 8; ++w) sum += red_s[w * 12 + tid];
          astore(&z_buf[bg * kT + tb + tid], sum);
        }
        __syncthreads();
      }
    }
    ++n;
    __syncthreads();
    if (tid == 0) astoreu(myflag, n);
    wait_flags(n);

    // ================= softmax over T + ctx =================
    if (gm < GB) {
      const int b = B0 + gm;
      if (tid < kT) soft_s[tid] = aload1(&z_buf[b * kT + tid]);
      __syncthreads();
      float mx = -1e30f;
      for (int i = 0; i < kT; ++i) mx = fmaxf(mx, soft_s[i]);
      float den = 0.f;
      for (int i = 0; i < kT; ++i) den += expf(soft_s[i] - mx);
      __syncthreads();
      if (tid < kT) soft_s[tid] = expf(soft_s[tid] - mx) / den;
      __syncthreads();
      {
        const int h0 = tid;
        float a0 = 0.f, a1 = 0.f, a2 = 0.f, a3 = 0.f;
        for (int tt = 0; tt < kT; tt += 4) {
          a0 += soft_s[tt + 0] * aload1(&hs_buf[((size_t)b * kT + tt + 0) * kH + h0]);
          a1 += soft_s[tt + 1] * aload1(&hs_buf[((size_t)b * kT + tt + 1) * kH + h0]);
          a2 += soft_s[tt + 2] * aload1(&hs_buf[((size_t)b * kT + tt + 2) * kH + h0]);
          a3 += soft_s[tt + 3] * aload1(&hs_buf[((size_t)b * kT + tt + 3) * kH + h0]);
        }
        astore(&ctx_ws[b * kH + h0], (a0 + a1) + (a2 + a3));
      }
    }
    ++n;
    __syncthreads();
    if (tid == 0) astoreu(myflag, n);
    wait_flags(n);

    // ================= sentence LSTM (two-pass GEMV) =================
    {
      float acc[4][2];
#pragma unroll
      for (int d = 0; d < 4; ++d) { acc[d][0] = 0.f; acc[d][1] = 0.f; }
      stage16_lin(ctx_ws + B0 * kH);  // pass A: x = ctx
      __syncthreads();
#pragma unroll 2
      for (int u = 0; u < 16; ++u) {
        const int chunk = 16 * jj + u;
        const int offH = ((chunk + bp) & 127) * 4;
        const float4 x0v = *(const float4*)&h_s[b0][offH];
        const float4 x1v = *(const float4*)&h_s[b1][offH];
#pragma unroll
        for (int d = 0; d < 4; ++d) {
          const float4 w = *(const float4*)&s_Wih[(size_t)grow(4 * cc + d) * kH + chunk * 4];
          acc[d][0] += dot4(w, x0v);
          acc[d][1] += dot4(w, x1v);
        }
      }
      __syncthreads();
      stage16_lin(sh_buf + (s & 1) * kB * kH + B0 * kH);  // pass B: h = sh
      __syncthreads();
#pragma unroll 2
      for (int u = 0; u < 16; ++u) {
        const int chunk = 16 * jj + u;
        const int offH = ((chunk + bp) & 127) * 4;
        const float4 h0v = *(const float4*)&h_s[b0][offH];
        const float4 h1v = *(const float4*)&h_s[b1][offH];
#pragma unroll
        for (int d = 0; d < 4; ++d) {
          const float4 w = *(const float4*)&s_Whh[(size_t)grow(4 * cc + d) * kH + chunk * 4];
          acc[d][0] += dot4(w, h0v);
          acc[d][1] += dot4(w, h1v);
        }
      }
#pragma unroll
      for (int d = 0; d < 4; ++d) {
        part_f[jj * 576 + lane * 9 + d * 2 + 0] = acc[d][0];
        part_f[jj * 576 + lane * 9 + d * 2 + 1] = acc[d][1];
      }
      __syncthreads();
      {
        const int c = tid >> 4, b = tid & 15;
        const int lp = (c >> 2) * 8 + (b >> 1), sl = (c & 3) * 2 + (b & 1);
        const int row = grow(c);
        float sum = s_bih[row] + s_bhh[row];
#pragma unroll
        for (int j = 0; j < 8; ++j) sum += part_f[j * 576 + lp * 9 + sl];
        gates_s[c][b] = sum;
      }
      __syncthreads();
      if (tid < HC * GB) {
        const int hcl = tid >> 4, b = tid & 15;
        const float gi = gates_s[hcl][b], gf = gates_s[8 + hcl][b];
        const float gg = gates_s[16 + hcl][b], go = gates_s[24 + hcl][b];
        const float c2 = sigmoidf(gf) * sc_s[hcl][b] + sigmoidf(gi) * tanhf(gg);
        const float h2 = sigmoidf(go) * tanhf(c2);
        sc_s[hcl][b] = c2;
        const int col = hc0 + hcl;
        astore(&sh_buf[((s + 1) & 1) * kB * kH + (B0 + b) * kH + col], h2);
        astore(&sent_hs[((size_t)(B0 + b) * kS + s) * kH + col], h2);
      }
    }
    ++n;
    __syncthreads();
    if (tid == 0) astoreu(myflag, n);
    if (s < kS - 1) prefetch(s + 1, 0);
    wait_flags(n);
  }

  // ================= final attention over S (group-local) =================
  {
    const int pair0 = gm * 6;
    for (int idx = tid; idx < 6 * 256; idx += NTH) {
      int pp = idx >> 8, hh2 = (idx & 255) * 2;
      const int pr = pair0 + pp;
      float2 v = aload2(&sent_hs[((size_t)(B0 + pr / kS) * kS + pr % kS) * kH + hh2]);
      *(float2*)&attn_f[pp * HP + hh2] = v;
    }
    __syncthreads();
    const int aa = tid;
    float dacc[6];
#pragma unroll
    for (int p = 0; p < 6; ++p) dacc[p] = 0.f;
    const float4* __restrict__ wk = (const float4*)(sa_Wk + (size_t)aa * kH);
    for (int k = 0; k < kH / 4; ++k) {
      float4 w = wk[k];
#pragma unroll
      for (int p = 0; p < 6; ++p)
        dacc[p] += dot4(w, *(const float4*)&attn_f[p * HP + k * 4]);
    }
    const float wv = sa_Wv[aa];
    const int ln = tid & 63, wid = tid >> 6;
#pragma unroll
    for (int p = 0; p < 6; ++p) {
      float v = wv * tanhf(dacc[p]);
      v += __shfl_down(v, 32); v += __shfl_down(v, 16); v += __shfl_down(v, 8);
      v += __shfl_down(v, 4);  v += __shfl_down(v, 2);  v += __shfl_down(v, 1);
      if (ln == 0) red_s[wid * 6 + p] = v;
    }
    __syncthreads();
    if (tid < 6) {
      float sum = 0.f;
#pragma unroll
      for (int w = 0; w < 8; ++w) sum += red_s[w * 6 + tid];
      astore(&z2_buf[B0 * kS + pair0 + tid], sum);
    }
  }
  ++n;
  __syncthreads();
  if (tid == 0) astoreu(myflag, n);
  wait_flags(n);

  // ================= final softmax + outputs =================
  if (gm < GB) {
    const int b = B0 + gm;
    if (tid < kS) soft_s[tid] = aload1(&z2_buf[b * kS + tid]);
    __syncthreads();
    float mx = -1e30f;
    for (int i = 0; i < kS; ++i) mx = fmaxf(mx, soft_s[i]);
    float den = 0.f;
    for (int i = 0; i < kS; ++i) den += expf(soft_s[i] - mx);
    __syncthreads();
    if (tid < kS) {
      float al = expf(soft_s[tid] - mx) / den;
      soft_s[tid] = al;
      out[kB * kH + b * kS + tid] = al;  // alpha
    }
    __syncthreads();
    {
      const int h0 = tid;
      float acc = 0.f;
      for (int s2 = 0; s2 < kS; ++s2)
        acc += soft_s[s2] * aload1(&sent_hs[((size_t)b * kS + s2) * kH + h0]);
      out[b * kH + h0] = acc;  // context
    }
  }
}

extern "C" void kernel_launch(void* const* d_in, const int* in_sizes, int n_in,
                              void* d_out, int out_size, void* d_ws, size_t ws_size,
                              hipStream_t stream) {
  (void)in_sizes; (void)n_in; (void)out_size; (void)ws_size;
  const int* captions = (const int*)d_in[0];
  const int* masks = (const int*)d_in[1];
  const float* embed_W = (const float*)d_in[2];
  const float* w_Wih = (const float*)d_in[3];
  const float* w_Whh = (const float*)d_in[4];
  const float* w_bih = (const float*)d_in[5];
  const float* w_bhh = (const float*)d_in[6];
  const float* s_Wih = (const float*)d_in[7];
  const float* s_Whh = (const float*)d_in[8];
  const float* s_bih = (const float*)d_in[9];
  const float* s_bhh = (const float*)d_in[10];
  const float* wa_Wk = (const float*)d_in[11];
  const float* wa_Wv = (const float*)d_in[12];
  const float* sa_Wk = (const float*)d_in[13];
  const float* sa_Wv = (const float*)d_in[14];
  float* out = (float*)d_out;
  float* ws = (float*)d_ws;

  void* args[] = {&captions, &masks, &embed_W, &w_Wih, &w_Whh, &w_bih, &w_bhh,
                  &s_Wih, &s_Whh, &s_bih, &s_bhh, &wa_Wk, &wa_Wv, &sa_Wk, &sa_Wv,
                  &out, &ws};
  hipLaunchCooperativeKernel((void*)ha_kernel, dim3(NWG), dim3(NTH), args, 0, stream);
}